// Round 1
// baseline (423.677 us; speedup 1.0000x reference)
//
#include <hip/hip_runtime.h>

#define NN 100000
#define NE 3200000

// ---------------- Layer 1 node transform ----------------
// y1[i]   = x[i] @ W_rel1                  (8 wide)  -> scattered along edges
// agg1[i] = x[i] @ W_root1 + b_rel1        (8 wide)  -> scatter target (init)
__global__ void node_layer1(const float* __restrict__ x,
                            const float* __restrict__ Wrel1,
                            const float* __restrict__ brel1,
                            const float* __restrict__ Wroot1,
                            float* __restrict__ y1,
                            float* __restrict__ agg1) {
    __shared__ float sW[16 * 8];
    __shared__ float sR[16 * 8];
    __shared__ float sb[8];
    int t = threadIdx.x;
    if (t < 128) { sW[t] = Wrel1[t]; sR[t] = Wroot1[t]; }
    if (t < 8)   { sb[t] = brel1[t]; }
    __syncthreads();

    int i = blockIdx.x * blockDim.x + t;
    if (i >= NN) return;

    const float4* xp = (const float4*)(x + (size_t)i * 16);
    float4 x0 = xp[0], x1 = xp[1], x2 = xp[2], x3 = xp[3];
    float xi[16] = {x0.x, x0.y, x0.z, x0.w, x1.x, x1.y, x1.z, x1.w,
                    x2.x, x2.y, x2.z, x2.w, x3.x, x3.y, x3.z, x3.w};

    float y[8], r[8];
#pragma unroll
    for (int j = 0; j < 8; ++j) { y[j] = 0.0f; r[j] = sb[j]; }
#pragma unroll
    for (int k = 0; k < 16; ++k) {
        float xv = xi[k];
#pragma unroll
        for (int j = 0; j < 8; ++j) {
            y[j] = fmaf(xv, sW[k * 8 + j], y[j]);
            r[j] = fmaf(xv, sR[k * 8 + j], r[j]);
        }
    }
    float4* yp = (float4*)(y1 + (size_t)i * 8);
    float4* ap = (float4*)(agg1 + (size_t)i * 8);
    yp[0] = make_float4(y[0], y[1], y[2], y[3]);
    yp[1] = make_float4(y[4], y[5], y[6], y[7]);
    ap[0] = make_float4(r[0], r[1], r[2], r[3]);
    ap[1] = make_float4(r[4], r[5], r[6], r[7]);
}

// ---------------- Edge scatters (8 threads per edge) ----------------
__global__ void scatter1(const int* __restrict__ src,
                         const int* __restrict__ dst,
                         const float* __restrict__ y1,
                         float* __restrict__ agg1) {
    int tid = blockIdx.x * blockDim.x + threadIdx.x;
    int e = tid >> 3, f = tid & 7;
    if (e >= NE) return;
    int s = src[e], d = dst[e];
    atomicAdd(&agg1[(size_t)d * 8 + f], y1[(size_t)s * 8 + f]);
}

// gathers relu(agg1[src]) -> agg2[dst]  (relu applied lazily, no h1 pass)
__global__ void scatter2(const int* __restrict__ src,
                         const int* __restrict__ dst,
                         const float* __restrict__ agg1,
                         float* __restrict__ agg2) {
    int tid = blockIdx.x * blockDim.x + threadIdx.x;
    int e = tid >> 3, f = tid & 7;
    if (e >= NE) return;
    int s = src[e], d = dst[e];
    float v = agg1[(size_t)s * 8 + f];
    v = v > 0.0f ? v : 0.0f;
    atomicAdd(&agg2[(size_t)d * 8 + f], v);
}

// ---------------- Fused tail: GraphConv2 combine + fc1 + fc2 + sum ----------------
__global__ void node_tail(const float* __restrict__ agg1,
                          const float* __restrict__ agg2,
                          const float* __restrict__ Wrel2,
                          const float* __restrict__ brel2,
                          const float* __restrict__ Wroot2,
                          const float* __restrict__ Wfc1,
                          const float* __restrict__ bfc1,
                          const float* __restrict__ Wfc2,
                          const float* __restrict__ bfc2,
                          float* __restrict__ out,
                          float* __restrict__ gsum) {
    __shared__ float sWrel2[8 * 16];
    __shared__ float sWroot2[8 * 16];
    __shared__ float sbrel2[16];
    __shared__ float sWfc1[16 * 32];
    __shared__ float sbfc1[32];
    __shared__ float sWfc2[32];
    __shared__ float sbfc2;
    __shared__ float wsum[4];

    int t = threadIdx.x;
    if (t < 128) { sWrel2[t] = Wrel2[t]; sWroot2[t] = Wroot2[t]; }
    for (int k = t; k < 512; k += 256) sWfc1[k] = Wfc1[k];
    if (t < 16) sbrel2[t] = brel2[t];
    if (t < 32) { sbfc1[t] = bfc1[t]; sWfc2[t] = Wfc2[t]; }
    if (t == 0) sbfc2 = bfc2[0];
    __syncthreads();

    int i = blockIdx.x * blockDim.x + t;
    float o = 0.0f;
    if (i < NN) {
        float h1v[8], s2[8];
        const float4* a1 = (const float4*)(agg1 + (size_t)i * 8);
        const float4* a2 = (const float4*)(agg2 + (size_t)i * 8);
        float4 a1a = a1[0], a1b = a1[1], a2a = a2[0], a2b = a2[1];
        h1v[0] = a1a.x; h1v[1] = a1a.y; h1v[2] = a1a.z; h1v[3] = a1a.w;
        h1v[4] = a1b.x; h1v[5] = a1b.y; h1v[6] = a1b.z; h1v[7] = a1b.w;
        s2[0] = a2a.x; s2[1] = a2a.y; s2[2] = a2a.z; s2[3] = a2a.w;
        s2[4] = a2b.x; s2[5] = a2b.y; s2[6] = a2b.z; s2[7] = a2b.w;
#pragma unroll
        for (int k = 0; k < 8; ++k) h1v[k] = h1v[k] > 0.0f ? h1v[k] : 0.0f;

        float h2[16];
#pragma unroll
        for (int j = 0; j < 16; ++j) h2[j] = sbrel2[j];
#pragma unroll
        for (int k = 0; k < 8; ++k) {
            float sv = s2[k], hv = h1v[k];
#pragma unroll
            for (int j = 0; j < 16; ++j) {
                h2[j] = fmaf(sv, sWrel2[k * 16 + j], h2[j]);
                h2[j] = fmaf(hv, sWroot2[k * 16 + j], h2[j]);
            }
        }
#pragma unroll
        for (int j = 0; j < 16; ++j) h2[j] = h2[j] > 0.0f ? h2[j] : 0.0f;

        o = sbfc2;
#pragma unroll
        for (int m = 0; m < 32; ++m) {
            float a = sbfc1[m];
#pragma unroll
            for (int j = 0; j < 16; ++j) a = fmaf(h2[j], sWfc1[j * 32 + m], a);
            a = a > 0.0f ? a : 0.0f;
            o = fmaf(a, sWfc2[m], o);
        }
        out[i] = o;
    }

    // block reduction of o -> gsum
    float v = o;
#pragma unroll
    for (int off = 32; off > 0; off >>= 1) v += __shfl_down(v, off);
    int lane = t & 63, w = t >> 6;
    if (lane == 0) wsum[w] = v;
    __syncthreads();
    if (t == 0) atomicAdd(gsum, wsum[0] + wsum[1] + wsum[2] + wsum[3]);
}

__global__ void subtract_mean(float* __restrict__ out,
                              const float* __restrict__ gsum) {
    int i = blockIdx.x * blockDim.x + threadIdx.x;
    if (i < NN) out[i] -= (*gsum) * (1.0f / (float)NN);
}

extern "C" void kernel_launch(void* const* d_in, const int* in_sizes, int n_in,
                              void* d_out, int out_size, void* d_ws, size_t ws_size,
                              hipStream_t stream) {
    const float* x      = (const float*)d_in[0];
    const int*   ei     = (const int*)d_in[1];   // [2, NE] int32 (harness converts int64)
    const float* Wrel1  = (const float*)d_in[2];
    const float* brel1  = (const float*)d_in[3];
    const float* Wroot1 = (const float*)d_in[4];
    const float* Wrel2  = (const float*)d_in[5];
    const float* brel2  = (const float*)d_in[6];
    const float* Wroot2 = (const float*)d_in[7];
    const float* Wfc1   = (const float*)d_in[8];
    const float* bfc1   = (const float*)d_in[9];
    const float* Wfc2   = (const float*)d_in[10];
    const float* bfc2   = (const float*)d_in[11];
    float* out = (float*)d_out;
    float* ws  = (float*)d_ws;

    float* y1   = ws;                 // 800000 floats
    float* agg1 = ws + 800000;        // 800000 floats (init by node_layer1)
    float* agg2 = ws + 1600000;       // 800000 floats (needs zeroing)
    float* gsum = ws + 2400000;       // 1 float      (needs zeroing)

    // zero agg2 + gsum in one contiguous memset
    hipMemsetAsync(agg2, 0, (800000 + 1) * sizeof(float), stream);

    const int* src = ei;
    const int* dst = ei + NE;

    node_layer1<<<(NN + 255) / 256, 256, 0, stream>>>(x, Wrel1, brel1, Wroot1, y1, agg1);

    int edge_threads = NE * 8;
    int edge_blocks = (edge_threads + 255) / 256;
    scatter1<<<edge_blocks, 256, 0, stream>>>(src, dst, y1, agg1);
    scatter2<<<edge_blocks, 256, 0, stream>>>(src, dst, agg1, agg2);

    node_tail<<<(NN + 255) / 256, 256, 0, stream>>>(agg1, agg2, Wrel2, brel2, Wroot2,
                                                    Wfc1, bfc1, Wfc2, bfc2, out, gsum);
    subtract_mean<<<(NN + 255) / 256, 256, 0, stream>>>(out, gsum);
}